// Round 1
// baseline (26.018 us; speedup 1.0000x reference)
//
#include <hip/hip_runtime.h>
#include <math.h>

#define TPB   512
#define EPB   64
#define NBLK  256

// LDS layout (float offsets)
#define ACT_OFF 0                 // [128][64] activations (reused h0/h1/h2/h3)
#define W1_OFF  8192              // [128][132] W1^T padded
#define W2_OFF  25088             // [64][132]  W2^T padded
#define W3_OFF  33536             // [32][68]   W3^T padded
#define PG_OFF  35712             // [8][64] partial gmf dot
#define SM_FLOATS 36224
#define SM_BYTES (SM_FLOATS * 4)  // 144,896 B

template<int NCHUNK, int ROWSTRIDE>
__device__ __forceinline__ void mlp_quad(const float* smW, int j0,
                                         const float* h,
                                         const float* __restrict__ bias,
                                         float acc[4])
{
  acc[0] = bias[j0+0]; acc[1] = bias[j0+1]; acc[2] = bias[j0+2]; acc[3] = bias[j0+3];
  const float4* r0 = (const float4*)(smW + (j0+0)*ROWSTRIDE);
  const float4* r1 = (const float4*)(smW + (j0+1)*ROWSTRIDE);
  const float4* r2 = (const float4*)(smW + (j0+2)*ROWSTRIDE);
  const float4* r3 = (const float4*)(smW + (j0+3)*ROWSTRIDE);
  #pragma unroll
  for (int c = 0; c < NCHUNK; ++c) {
    float4 w0 = r0[c], w1 = r1[c], w2 = r2[c], w3 = r3[c];
    float x0 = h[4*c+0], x1 = h[4*c+1], x2 = h[4*c+2], x3 = h[4*c+3];
    acc[0] += x0*w0.x; acc[1] += x0*w1.x; acc[2] += x0*w2.x; acc[3] += x0*w3.x;
    acc[0] += x1*w0.y; acc[1] += x1*w1.y; acc[2] += x1*w2.y; acc[3] += x1*w3.y;
    acc[0] += x2*w0.z; acc[1] += x2*w1.z; acc[2] += x2*w2.z; acc[3] += x2*w3.z;
    acc[0] += x3*w0.w; acc[1] += x3*w1.w; acc[2] += x3*w2.w; acc[3] += x3*w3.w;
  }
}

__launch_bounds__(TPB, 2)
__global__ void ncf_fused(
    const int* __restrict__ user, const int* __restrict__ item,
    const float* __restrict__ Wug, const float* __restrict__ bug,
    const float* __restrict__ Wum, const float* __restrict__ bum,
    const float* __restrict__ Wig, const float* __restrict__ big,
    const float* __restrict__ Wim, const float* __restrict__ bim,
    const float* __restrict__ W1, const float* __restrict__ b1,
    const float* __restrict__ W2, const float* __restrict__ b2,
    const float* __restrict__ W3, const float* __restrict__ b3,
    const float* __restrict__ Wp, const float* __restrict__ bp,
    float* __restrict__ out)
{
  extern __shared__ __align__(16) float sm[];
  const int t    = threadIdx.x;
  const int lane = t & 63;
  const int w    = t >> 6;
  const int e0   = blockIdx.x * EPB;

  // ---- stage transposed (padded) weights into LDS ----
  #pragma unroll
  for (int r = 0; r < 32; ++r) {                 // W1: 128x128
    int idx = r*TPB + t; int j = idx & 127, i = idx >> 7;
    sm[W1_OFF + j*132 + i] = W1[i*128 + j];
  }
  #pragma unroll
  for (int r = 0; r < 16; ++r) {                 // W2: 128x64
    int idx = r*TPB + t; int j = idx & 63, i = idx >> 6;
    sm[W2_OFF + j*132 + i] = W2[i*64 + j];
  }
  #pragma unroll
  for (int r = 0; r < 4; ++r) {                  // W3: 64x32
    int idx = r*TPB + t; int j = idx & 31, i = idx >> 5;
    sm[W3_OFF + j*68 + i] = W3[i*32 + j];
  }

  // ---- gather embeddings: element = lane, k-chunk [w*8, w*8+8) per wave ----
  {
    const int e  = lane;
    const int k0 = w * 8;
    const int u  = user[e0 + e];
    const int it = item[e0 + e];
    const float4* um4  = (const float4*)(Wum + (size_t)u  * 64 + k0);
    const float4* im4  = (const float4*)(Wim + (size_t)it * 64 + k0);
    const float4* ug4  = (const float4*)(Wug + (size_t)u  * 64 + k0);
    const float4* ig4  = (const float4*)(Wig + (size_t)it * 64 + k0);
    const float4* bum4 = (const float4*)(bum + k0);
    const float4* bim4 = (const float4*)(bim + k0);
    const float4* bug4 = (const float4*)(bug + k0);
    const float4* big4 = (const float4*)(big + k0);
    const float4* wp4  = (const float4*)(Wp  + k0);
    float psum = 0.f;
    #pragma unroll
    for (int c = 0; c < 2; ++c) {
      int kk = k0 + 4*c;
      float4 a = um4[c], ab = bum4[c];
      sm[ACT_OFF + (kk+0)*64 + e] = fmaxf(a.x + ab.x, 0.f);
      sm[ACT_OFF + (kk+1)*64 + e] = fmaxf(a.y + ab.y, 0.f);
      sm[ACT_OFF + (kk+2)*64 + e] = fmaxf(a.z + ab.z, 0.f);
      sm[ACT_OFF + (kk+3)*64 + e] = fmaxf(a.w + ab.w, 0.f);
      float4 b = im4[c], bb = bim4[c];
      sm[ACT_OFF + (64+kk+0)*64 + e] = fmaxf(b.x + bb.x, 0.f);
      sm[ACT_OFF + (64+kk+1)*64 + e] = fmaxf(b.y + bb.y, 0.f);
      sm[ACT_OFF + (64+kk+2)*64 + e] = fmaxf(b.z + bb.z, 0.f);
      sm[ACT_OFF + (64+kk+3)*64 + e] = fmaxf(b.w + bb.w, 0.f);
      float4 g1 = ug4[c], g1b = bug4[c];
      float4 g2 = ig4[c], g2b = big4[c];
      float4 wv = wp4[c];
      psum += fmaxf(g1.x+g1b.x,0.f) * fmaxf(g2.x+g2b.x,0.f) * wv.x;
      psum += fmaxf(g1.y+g1b.y,0.f) * fmaxf(g2.y+g2b.y,0.f) * wv.y;
      psum += fmaxf(g1.z+g1b.z,0.f) * fmaxf(g2.z+g2b.z,0.f) * wv.z;
      psum += fmaxf(g1.w+g1b.w,0.f) * fmaxf(g2.w+g2b.w,0.f) * wv.w;
    }
    sm[PG_OFF + w*64 + e] = psum;
  }
  __syncthreads();

  float h[128];
  #pragma unroll
  for (int i = 0; i < 128; ++i) h[i] = sm[ACT_OFF + i*64 + lane];
  __syncthreads();

  // ---- layer 1: 128 -> 128, wave w owns j in [w*16, w*16+16) ----
  #pragma unroll 1
  for (int q = 0; q < 4; ++q) {
    const int j0 = w*16 + q*4;
    float acc[4];
    mlp_quad<32,132>(sm + W1_OFF, j0, h, b1, acc);
    sm[ACT_OFF + (j0+0)*64 + lane] = fmaxf(acc[0], 0.f);
    sm[ACT_OFF + (j0+1)*64 + lane] = fmaxf(acc[1], 0.f);
    sm[ACT_OFF + (j0+2)*64 + lane] = fmaxf(acc[2], 0.f);
    sm[ACT_OFF + (j0+3)*64 + lane] = fmaxf(acc[3], 0.f);
  }
  __syncthreads();
  #pragma unroll
  for (int i = 0; i < 128; ++i) h[i] = sm[ACT_OFF + i*64 + lane];
  __syncthreads();

  // ---- layer 2: 128 -> 64, wave w owns j in [w*8, w*8+8) ----
  #pragma unroll 1
  for (int q = 0; q < 2; ++q) {
    const int j0 = w*8 + q*4;
    float acc[4];
    mlp_quad<32,132>(sm + W2_OFF, j0, h, b2, acc);
    sm[ACT_OFF + (j0+0)*64 + lane] = fmaxf(acc[0], 0.f);
    sm[ACT_OFF + (j0+1)*64 + lane] = fmaxf(acc[1], 0.f);
    sm[ACT_OFF + (j0+2)*64 + lane] = fmaxf(acc[2], 0.f);
    sm[ACT_OFF + (j0+3)*64 + lane] = fmaxf(acc[3], 0.f);
  }
  __syncthreads();
  #pragma unroll
  for (int i = 0; i < 64; ++i) h[i] = sm[ACT_OFF + i*64 + lane];
  __syncthreads();

  // ---- layer 3: 64 -> 32, wave w owns j in [w*4, w*4+4) ----
  {
    const int j0 = w*4;
    float acc[4];
    mlp_quad<16,68>(sm + W3_OFF, j0, h, b3, acc);
    sm[ACT_OFF + (j0+0)*64 + lane] = fmaxf(acc[0], 0.f);
    sm[ACT_OFF + (j0+1)*64 + lane] = fmaxf(acc[1], 0.f);
    sm[ACT_OFF + (j0+2)*64 + lane] = fmaxf(acc[2], 0.f);
    sm[ACT_OFF + (j0+3)*64 + lane] = fmaxf(acc[3], 0.f);
  }
  __syncthreads();

  // ---- final: concat([gmf(64), h3(32)]) @ Wp + bp -> sigmoid ----
  if (t < 64) {
    const int e = t;
    float x = bp[0];
    #pragma unroll
    for (int s = 0; s < 8; ++s) x += sm[PG_OFF + s*64 + e];
    #pragma unroll
    for (int j = 0; j < 32; ++j) x += sm[ACT_OFF + j*64 + e] * Wp[64 + j];
    out[e0 + e] = 1.f / (1.f + expf(-x));
  }
}

extern "C" void kernel_launch(void* const* d_in, const int* in_sizes, int n_in,
                              void* d_out, int out_size, void* d_ws, size_t ws_size,
                              hipStream_t stream) {
  const int*   user = (const int*)  d_in[0];
  const int*   item = (const int*)  d_in[1];
  const float* Wug  = (const float*)d_in[2];
  const float* bug  = (const float*)d_in[3];
  const float* Wum  = (const float*)d_in[4];
  const float* bum  = (const float*)d_in[5];
  const float* Wig  = (const float*)d_in[6];
  const float* big  = (const float*)d_in[7];
  const float* Wim  = (const float*)d_in[8];
  const float* bim  = (const float*)d_in[9];
  const float* W1   = (const float*)d_in[10];
  const float* b1   = (const float*)d_in[11];
  const float* W2   = (const float*)d_in[12];
  const float* b2   = (const float*)d_in[13];
  const float* W3   = (const float*)d_in[14];
  const float* b3   = (const float*)d_in[15];
  const float* Wp   = (const float*)d_in[16];
  const float* bp   = (const float*)d_in[17];
  float* out = (float*)d_out;

  (void)hipFuncSetAttribute(reinterpret_cast<const void*>(ncf_fused),
                            hipFuncAttributeMaxDynamicSharedMemorySize, SM_BYTES);
  ncf_fused<<<NBLK, TPB, SM_BYTES, stream>>>(
      user, item, Wug, bug, Wum, bum, Wig, big, Wim, bim,
      W1, b1, W2, b2, W3, b3, Wp, bp, out);
}

// Round 2
// 12.631 us; speedup vs baseline: 2.0598x; 2.0598x over previous
//
#include <hip/hip_runtime.h>
#include <math.h>

typedef __attribute__((ext_vector_type(8))) short bf16x8;
typedef __attribute__((ext_vector_type(4))) float f32x4;

#define TPB  256
#define NBLK 256

// LDS byte offsets (all 16B-aligned). Row strides 272B/144B: lanes 0-15 hit
// each bank exactly 2x on b128 reads -> 2-way conflict = free (m136).
#define W1T_OFF 0                       // [128 n][136 k] bf16, stride 272B
#define W2T_OFF 34816                   // [64  n][136 k] bf16, stride 272B
#define W3T_OFF 52224                   // [32  n][72  k] bf16, stride 144B
#define SCR_OFF 56832                   // per-wave [16][136] bf16 scratch
#define SCR_PW  4352
#define SM_BYTES (SCR_OFF + 4*SCR_PW)   // 74240 B

__device__ __forceinline__ unsigned short f2bf(float a){
  unsigned ua = __float_as_uint(a);
  return (unsigned short)((ua + 0x7FFFu + ((ua>>16)&1u)) >> 16);   // RNE
}
__device__ __forceinline__ unsigned int f2bf_pk(float a, float b){
  return (unsigned int)f2bf(a) | ((unsigned int)f2bf(b) << 16);
}
// 8 values relu(a+ba)||relu(b+bb) -> A-fragment (k ascending j=0..7)
__device__ __forceinline__ bf16x8 mk_frag(float4 a, float4 ba, float4 b, float4 bb){
  union { bf16x8 v; unsigned int u[4]; } o;
  o.u[0] = f2bf_pk(fmaxf(a.x+ba.x,0.f), fmaxf(a.y+ba.y,0.f));
  o.u[1] = f2bf_pk(fmaxf(a.z+ba.z,0.f), fmaxf(a.w+ba.w,0.f));
  o.u[2] = f2bf_pk(fmaxf(b.x+bb.x,0.f), fmaxf(b.y+bb.y,0.f));
  o.u[3] = f2bf_pk(fmaxf(b.z+bb.z,0.f), fmaxf(b.w+bb.w,0.f));
  return o.v;
}

__launch_bounds__(TPB, 2)
__global__ void ncf_mfma(
    const int* __restrict__ user, const int* __restrict__ item,
    const float* __restrict__ Wug, const float* __restrict__ bug,
    const float* __restrict__ Wum, const float* __restrict__ bum,
    const float* __restrict__ Wig, const float* __restrict__ big,
    const float* __restrict__ Wim, const float* __restrict__ bim,
    const float* __restrict__ W1, const float* __restrict__ b1,
    const float* __restrict__ W2, const float* __restrict__ b2,
    const float* __restrict__ W3, const float* __restrict__ b3,
    const float* __restrict__ Wp, const float* __restrict__ bp,
    float* __restrict__ out)
{
  extern __shared__ __align__(16) char sm[];
  const int t    = threadIdx.x;
  const int lane = t & 63;
  const int w    = t >> 6;
  const int r    = lane & 15;        // A/B row|col within 16-tile
  const int g    = lane >> 4;        // k-group
  const int gb   = blockIdx.x * 64 + w * 16 + r;   // this lane's batch row

  // ---- gather: issue all global loads early (overlap with staging) ----
  const int u  = user[gb];
  const int it = item[gb];
  const float* up = Wum + (size_t)u  * 64;
  const float* ip = Wim + (size_t)it * 64;
  float4 mu0 = *(const float4*)(up + 8*g);
  float4 mu1 = *(const float4*)(up + 8*g + 4);
  float4 mu2 = *(const float4*)(up + 32 + 8*g);
  float4 mu3 = *(const float4*)(up + 32 + 8*g + 4);
  float4 mi0 = *(const float4*)(ip + 8*g);
  float4 mi1 = *(const float4*)(ip + 8*g + 4);
  float4 mi2 = *(const float4*)(ip + 32 + 8*g);
  float4 mi3 = *(const float4*)(ip + 32 + 8*g + 4);
  float4 bu0 = *(const float4*)(bum + 8*g);
  float4 bu1 = *(const float4*)(bum + 8*g + 4);
  float4 bu2 = *(const float4*)(bum + 32 + 8*g);
  float4 bu3 = *(const float4*)(bum + 32 + 8*g + 4);
  float4 bi0 = *(const float4*)(bim + 8*g);
  float4 bi1 = *(const float4*)(bim + 8*g + 4);
  float4 bi2 = *(const float4*)(bim + 32 + 8*g);
  float4 bi3 = *(const float4*)(bim + 32 + 8*g + 4);

  const float* ugp = Wug + (size_t)u  * 64 + 16*g;
  const float* igp = Wig + (size_t)it * 64 + 16*g;
  float4 ga[4], gi[4], gba[4], gbb[4], wpv[4];
  #pragma unroll
  for (int c = 0; c < 4; ++c) {
    ga[c]  = *(const float4*)(ugp + 4*c);
    gi[c]  = *(const float4*)(igp + 4*c);
    gba[c] = *(const float4*)(bug + 16*g + 4*c);
    gbb[c] = *(const float4*)(big + 16*g + 4*c);
    wpv[c] = *(const float4*)(Wp  + 16*g + 4*c);
  }
  // bias / final-weight preloads for the tower
  float b1v[8], b2v[4], b3v[2], wp3[2];
  #pragma unroll
  for (int i = 0; i < 8; ++i) b1v[i] = b1[i*16 + r];
  #pragma unroll
  for (int i = 0; i < 4; ++i) b2v[i] = b2[i*16 + r];
  #pragma unroll
  for (int i = 0; i < 2; ++i) { b3v[i] = b3[i*16 + r]; wp3[i] = Wp[64 + i*16 + r]; }
  const float bpv = bp[0];

  // ---- stage weights -> LDS as bf16 [n][k] (transposed, packed pairs) ----
  #pragma unroll
  for (int i = 0; i < 32; ++i) {                 // W1: 128k x 128n
    int p = i*TPB + t; int n = p & 127, kp = p >> 7;
    float f0 = W1[(2*kp)*128 + n], f1 = W1[(2*kp+1)*128 + n];
    *(unsigned int*)(sm + W1T_OFF + n*272 + kp*4) = f2bf_pk(f0, f1);
  }
  #pragma unroll
  for (int i = 0; i < 16; ++i) {                 // W2: 128k x 64n
    int p = i*TPB + t; int n = p & 63, kp = p >> 6;
    float f0 = W2[(2*kp)*64 + n], f1 = W2[(2*kp+1)*64 + n];
    *(unsigned int*)(sm + W2T_OFF + n*272 + kp*4) = f2bf_pk(f0, f1);
  }
  #pragma unroll
  for (int i = 0; i < 4; ++i) {                  // W3: 64k x 32n
    int p = i*TPB + t; int n = p & 31, kp = p >> 5;
    float f0 = W3[(2*kp)*32 + n], f1 = W3[(2*kp+1)*32 + n];
    *(unsigned int*)(sm + W3T_OFF + n*144 + kp*4) = f2bf_pk(f0, f1);
  }

  // ---- GMF (pure f32, exact): partial over this lane's 16 cols ----
  float psum = 0.f;
  #pragma unroll
  for (int c = 0; c < 4; ++c) {
    psum += fmaxf(ga[c].x+gba[c].x,0.f) * fmaxf(gi[c].x+gbb[c].x,0.f) * wpv[c].x;
    psum += fmaxf(ga[c].y+gba[c].y,0.f) * fmaxf(gi[c].y+gbb[c].y,0.f) * wpv[c].y;
    psum += fmaxf(ga[c].z+gba[c].z,0.f) * fmaxf(gi[c].z+gbb[c].z,0.f) * wpv[c].z;
    psum += fmaxf(ga[c].w+gba[c].w,0.f) * fmaxf(gi[c].w+gbb[c].w,0.f) * wpv[c].w;
  }

  // ---- layer-1 A fragments straight from the gather (no LDS) ----
  // K order: [user-mlp 0..63 | item-mlp 64..127]  -> steps 0,1,2,3
  bf16x8 afr[4];
  afr[0] = mk_frag(mu0, bu0, mu1, bu1);
  afr[1] = mk_frag(mu2, bu2, mu3, bu3);
  afr[2] = mk_frag(mi0, bi0, mi1, bi1);
  afr[3] = mk_frag(mi2, bi2, mi3, bi3);

  __syncthreads();   // weights staged; the only block-wide barrier

  char* scr = sm + SCR_OFF + w * SCR_PW;   // wave-private scratch

  // ---- layer 1: [16,128] @ [128,128] ----
  #pragma unroll
  for (int nt = 0; nt < 8; ++nt) {
    f32x4 acc = {b1v[nt], b1v[nt], b1v[nt], b1v[nt]};
    #pragma unroll
    for (int s = 0; s < 4; ++s) {
      bf16x8 bf = *(const bf16x8*)(sm + W1T_OFF + (nt*16 + r)*272 + s*64 + g*16);
      acc = __builtin_amdgcn_mfma_f32_16x16x32_bf16(afr[s], bf, acc, 0, 0, 0);
    }
    #pragma unroll
    for (int q = 0; q < 4; ++q)   // D: col = nt*16+r, rows = 4g+q
      *(unsigned short*)(scr + (4*g + q)*272 + (nt*16 + r)*2) = f2bf(fmaxf(acc[q], 0.f));
  }

  // ---- layer 2: [16,128] @ [128,64] ----
  bf16x8 a2[4];
  #pragma unroll
  for (int s = 0; s < 4; ++s)
    a2[s] = *(const bf16x8*)(scr + r*272 + s*64 + g*16);
  #pragma unroll
  for (int nt = 0; nt < 4; ++nt) {
    f32x4 acc = {b2v[nt], b2v[nt], b2v[nt], b2v[nt]};
    #pragma unroll
    for (int s = 0; s < 4; ++s) {
      bf16x8 bf = *(const bf16x8*)(sm + W2T_OFF + (nt*16 + r)*272 + s*64 + g*16);
      acc = __builtin_amdgcn_mfma_f32_16x16x32_bf16(a2[s], bf, acc, 0, 0, 0);
    }
    #pragma unroll
    for (int q = 0; q < 4; ++q)   // H2 layout [16][72] bf16 in same scratch
      *(unsigned short*)(scr + (4*g + q)*144 + (nt*16 + r)*2) = f2bf(fmaxf(acc[q], 0.f));
  }

  // ---- layer 3: [16,64] @ [64,32], keep result in f32 regs ----
  bf16x8 a3[2];
  #pragma unroll
  for (int s = 0; s < 2; ++s)
    a3[s] = *(const bf16x8*)(scr + r*144 + s*64 + g*16);
  float h3p[4] = {0.f, 0.f, 0.f, 0.f};
  #pragma unroll
  for (int nt = 0; nt < 2; ++nt) {
    f32x4 acc = {b3v[nt], b3v[nt], b3v[nt], b3v[nt]};
    #pragma unroll
    for (int s = 0; s < 2; ++s) {
      bf16x8 bf = *(const bf16x8*)(sm + W3T_OFF + (nt*16 + r)*144 + s*64 + g*16);
      acc = __builtin_amdgcn_mfma_f32_16x16x32_bf16(a3[s], bf, acc, 0, 0, 0);
    }
    #pragma unroll
    for (int q = 0; q < 4; ++q)
      h3p[q] += fmaxf(acc[q], 0.f) * wp3[nt];   // * Wp[64 + nt*16 + r]
  }

  // ---- final reduce in wave-private scratch (f32 [16][20]) ----
  float* scf = (float*)scr;
  #pragma unroll
  for (int q = 0; q < 4; ++q) scf[(4*g + q)*20 + r] = h3p[q];  // h3 col-partials
  scf[r*20 + 16 + g] = psum;                                   // gmf g-partials
  __builtin_amdgcn_wave_barrier();  // ordering hint only; same-wave lgkmcnt applies

  if (lane < 16) {
    float x = bpv;
    const float4* row = (const float4*)(scf + lane*20);
    #pragma unroll
    for (int i = 0; i < 5; ++i) { float4 v = row[i]; x += v.x + v.y + v.z + v.w; }
    out[blockIdx.x*64 + w*16 + lane] = 1.f / (1.f + expf(-x));
  }
}

extern "C" void kernel_launch(void* const* d_in, const int* in_sizes, int n_in,
                              void* d_out, int out_size, void* d_ws, size_t ws_size,
                              hipStream_t stream) {
  const int*   user = (const int*)  d_in[0];
  const int*   item = (const int*)  d_in[1];
  const float* Wug  = (const float*)d_in[2];
  const float* bug  = (const float*)d_in[3];
  const float* Wum  = (const float*)d_in[4];
  const float* bum  = (const float*)d_in[5];
  const float* Wig  = (const float*)d_in[6];
  const float* big  = (const float*)d_in[7];
  const float* Wim  = (const float*)d_in[8];
  const float* bim  = (const float*)d_in[9];
  const float* W1   = (const float*)d_in[10];
  const float* b1   = (const float*)d_in[11];
  const float* W2   = (const float*)d_in[12];
  const float* b2   = (const float*)d_in[13];
  const float* W3   = (const float*)d_in[14];
  const float* b3   = (const float*)d_in[15];
  const float* Wp   = (const float*)d_in[16];
  const float* bp   = (const float*)d_in[17];
  float* out = (float*)d_out;

  (void)hipFuncSetAttribute(reinterpret_cast<const void*>(ncf_mfma),
                            hipFuncAttributeMaxDynamicSharedMemorySize, SM_BYTES);
  ncf_mfma<<<NBLK, TPB, SM_BYTES, stream>>>(
      user, item, Wug, bug, Wum, bum, Wig, big, Wim, bim,
      W1, b1, W2, b2, W3, b3, Wp, bp, out);
}